// Round 1
// baseline (5359.553 us; speedup 1.0000x reference)
//
#include <hip/hip_runtime.h>
#include <hip/hip_bf16.h>

typedef __hip_bfloat16 bf16;

#define HEADS 16
#define HDIM  64
#define DIM   1024
#define SEQ   2048
#define BATCH 4
#define BS    (BATCH * SEQ)   // 8192

// ---------------------------------------------------------------------------
// Shared inner tile: acc[i][j] += sum_k A[tm*4+i][k] * B[tn+16*j][k], k=0..63
// Column mapping tn+16*j keeps B-operand LDS reads at <=2-way bank aliasing.
// ---------------------------------------------------------------------------
__device__ __forceinline__ void gemm_tile_64(const float (*As)[68], const float (*Bs)[68],
                                             int tm, int tn, float acc[4][4])
{
#pragma unroll
    for (int kk = 0; kk < 64; kk += 4) {
        float4 a[4], b[4];
#pragma unroll
        for (int i = 0; i < 4; ++i) a[i] = *(const float4*)&As[tm * 4 + i][kk];
#pragma unroll
        for (int j = 0; j < 4; ++j) b[j] = *(const float4*)&Bs[tn + 16 * j][kk];
#pragma unroll
        for (int i = 0; i < 4; ++i)
#pragma unroll
            for (int j = 0; j < 4; ++j)
                acc[i][j] += a[i].x * b[j].x + a[i].y * b[j].y
                           + a[i].z * b[j].z + a[i].w * b[j].w;
    }
}

// Load a 64x64 bf16 tile (row stride 64) into fp32 LDS tile [64][68].
__device__ __forceinline__ void load_tile64(const bf16* __restrict__ g, float (*dst)[68], int tid)
{
#pragma unroll
    for (int p = 0; p < 2; ++p) {
        int idx = tid + p * 256;
        int r = idx >> 3, c = (idx & 7) << 3;
        uint4 u = *(const uint4*)&g[r * HDIM + c];
        const bf16* hh = reinterpret_cast<const bf16*>(&u);
#pragma unroll
        for (int j = 0; j < 8; ++j) dst[r][c + j] = __bfloat162float(hh[j]);
    }
}

// ---------------------------------------------------------------------------
// Kernel 1: QKV projections.  X:(BS,DIM) fp32, W:(DIM,DIM) fp32 (out-feature
// rows, nn.Linear x@W^T).  Output bf16 in (B,H,S,HDIM).
// ---------------------------------------------------------------------------
__global__ __launch_bounds__(256) void proj_qkv_kernel(
    const float* __restrict__ Qin, const float* __restrict__ Kin, const float* __restrict__ Vin,
    const float* __restrict__ Wq, const float* __restrict__ Wk, const float* __restrict__ Wv,
    bf16* __restrict__ qo, bf16* __restrict__ ko, bf16* __restrict__ vo)
{
    __shared__ float Xs[64][68];
    __shared__ float Ws[64][68];

    const float* X; const float* W; bf16* O;
    if (blockIdx.z == 0)      { X = Qin; W = Wq; O = qo; }
    else if (blockIdx.z == 1) { X = Kin; W = Wk; O = ko; }
    else                      { X = Vin; W = Wv; O = vo; }

    const int tid = threadIdx.x;
    const int tm = tid >> 4, tn = tid & 15;
    const int m0 = blockIdx.y * 64;
    const int n0 = blockIdx.x * 64;   // == head * 64

    float acc[4][4] = {};

    for (int k0 = 0; k0 < DIM; k0 += 64) {
#pragma unroll
        for (int p = 0; p < 4; ++p) {
            int idx = tid + p * 256;
            int r = idx >> 4, c = (idx & 15) << 2;
            *(float4*)&Xs[r][c] = *(const float4*)&X[(size_t)(m0 + r) * DIM + k0 + c];
            *(float4*)&Ws[r][c] = *(const float4*)&W[(size_t)(n0 + r) * DIM + k0 + c];
        }
        __syncthreads();
        gemm_tile_64(Xs, Ws, tm, tn, acc);
        __syncthreads();
    }

    const int h = blockIdx.x;   // 64-wide n-tile == exactly one head
#pragma unroll
    for (int i = 0; i < 4; ++i) {
        int m = m0 + tm * 4 + i;
        int bb = m >> 11;          // / SEQ
        int ss = m & (SEQ - 1);
        size_t base = ((size_t)(bb * HEADS + h) * SEQ + ss) * HDIM;
#pragma unroll
        for (int j = 0; j < 4; ++j)
            O[base + tn + 16 * j] = __float2bfloat16(acc[i][j]);
    }
}

// ---------------------------------------------------------------------------
// Kernel 2: causal attention for one (b, h, 64-row q-tile).
// Pass 1: online row max / sum-exp.  Pass 2: recompute scores, write softmax
// weights to global (fp32), accumulate PV in registers.  Upper-triangle tiles
// are zero-filled (reference softmax gives exact zeros there).
// ---------------------------------------------------------------------------
__global__ __launch_bounds__(256) void attn_kernel(
    const bf16* __restrict__ qws, const bf16* __restrict__ kws, const bf16* __restrict__ vws,
    float* __restrict__ weights, bf16* __restrict__ attn_out)
{
    __shared__ float Qs[64][68];
    __shared__ float KVs[64][68];
    __shared__ float Ps[64][68];
    __shared__ float m_row[64], l_row[64], il_row[64];

    const int tid = threadIdx.x;
    const int tm = tid >> 4, tn = tid & 15;
    const int qt = blockIdx.x;
    const int h = blockIdx.y, b = blockIdx.z;
    const int bh = b * HEADS + h;
    const int q0 = qt * 64;

    load_tile64(qws + ((size_t)bh * SEQ + q0) * HDIM, Qs, tid);
    if (tid < 64) { m_row[tid] = -1e30f; l_row[tid] = 0.0f; }
    __syncthreads();

    // ---- pass 1: row stats ----
    for (int kt = 0; kt <= qt; ++kt) {
        load_tile64(kws + ((size_t)bh * SEQ + kt * 64) * HDIM, KVs, tid);
        __syncthreads();
        float s[4][4] = {};
        gemm_tile_64(Qs, KVs, tm, tn, s);
        const bool diag = (kt == qt);
#pragma unroll
        for (int i = 0; i < 4; ++i) {
            int r = tm * 4 + i;
#pragma unroll
            for (int j = 0; j < 4; ++j) {
                s[i][j] *= 0.125f;
                if (diag && (tn + 16 * j > r)) s[i][j] = -1e30f;
            }
        }
#pragma unroll
        for (int i = 0; i < 4; ++i) {
            int r = tm * 4 + i;
            float tmax = fmaxf(fmaxf(s[i][0], s[i][1]), fmaxf(s[i][2], s[i][3]));
            tmax = fmaxf(tmax, __shfl_xor(tmax, 1));
            tmax = fmaxf(tmax, __shfl_xor(tmax, 2));
            tmax = fmaxf(tmax, __shfl_xor(tmax, 4));
            tmax = fmaxf(tmax, __shfl_xor(tmax, 8));
            float mo = m_row[r];
            float mn = fmaxf(mo, tmax);
            float ps = __expf(s[i][0] - mn) + __expf(s[i][1] - mn)
                     + __expf(s[i][2] - mn) + __expf(s[i][3] - mn);
            ps += __shfl_xor(ps, 1);
            ps += __shfl_xor(ps, 2);
            ps += __shfl_xor(ps, 4);
            ps += __shfl_xor(ps, 8);
            if (tn == 0) {
                l_row[r] = l_row[r] * __expf(mo - mn) + ps;
                m_row[r] = mn;
            }
        }
        __syncthreads();
    }
    if (tid < 64) il_row[tid] = 1.0f / l_row[tid];
    __syncthreads();

    // ---- pass 2: weights + PV ----
    float o[4][4] = {};
    for (int kt = 0; kt <= qt; ++kt) {
        load_tile64(kws + ((size_t)bh * SEQ + kt * 64) * HDIM, KVs, tid);
        __syncthreads();
        float s[4][4] = {};
        gemm_tile_64(Qs, KVs, tm, tn, s);
        const bool diag = (kt == qt);
        const size_t wbase = ((size_t)bh * SEQ + q0) * SEQ + kt * 64;
#pragma unroll
        for (int i = 0; i < 4; ++i) {
            int r = tm * 4 + i;
            float mr = m_row[r], il = il_row[r];
#pragma unroll
            for (int j = 0; j < 4; ++j) {
                float sv = s[i][j] * 0.125f;
                if (diag && (tn + 16 * j > r)) sv = -1e30f;
                float w = __expf(sv - mr) * il;
                weights[wbase + (size_t)r * SEQ + tn + 16 * j] = w;
                Ps[r][tn + 16 * j] = w;
            }
        }
        __syncthreads();                       // Ps complete, KVs free
        load_tile64(vws + ((size_t)bh * SEQ + kt * 64) * HDIM, KVs, tid);
        __syncthreads();
#pragma unroll
        for (int kk = 0; kk < 64; kk += 4) {
            float4 a[4];
#pragma unroll
            for (int i = 0; i < 4; ++i) a[i] = *(const float4*)&Ps[tm * 4 + i][kk];
            float4 b0 = *(const float4*)&KVs[kk + 0][tn * 4];
            float4 b1 = *(const float4*)&KVs[kk + 1][tn * 4];
            float4 b2 = *(const float4*)&KVs[kk + 2][tn * 4];
            float4 b3 = *(const float4*)&KVs[kk + 3][tn * 4];
#pragma unroll
            for (int i = 0; i < 4; ++i) {
                o[i][0] += a[i].x * b0.x + a[i].y * b1.x + a[i].z * b2.x + a[i].w * b3.x;
                o[i][1] += a[i].x * b0.y + a[i].y * b1.y + a[i].z * b2.y + a[i].w * b3.y;
                o[i][2] += a[i].x * b0.z + a[i].y * b1.z + a[i].z * b2.z + a[i].w * b3.z;
                o[i][3] += a[i].x * b0.w + a[i].y * b1.w + a[i].z * b2.w + a[i].w * b3.w;
            }
        }
        __syncthreads();
    }

    // write O tile (b, s, h*64 + d), d = tn*4+j contiguous -> 8B packed store
#pragma unroll
    for (int i = 0; i < 4; ++i) {
        int q = q0 + tm * 4 + i;
        union { bf16 hv[4]; uint2 u; } pk;
#pragma unroll
        for (int j = 0; j < 4; ++j) pk.hv[j] = __float2bfloat16(o[i][j]);
        *(uint2*)&attn_out[((size_t)(b * SEQ + q)) * DIM + h * HDIM + tn * 4] = pk.u;
    }

    // zero-fill masked (upper-triangle) columns of this q-tile's weight rows
    const int zc0 = (qt + 1) * 64;
    if (zc0 < SEQ) {
        const int nc4 = (SEQ - zc0) >> 2;
        const size_t base = ((size_t)bh * SEQ + q0) * SEQ + zc0;
        const float4 z = make_float4(0.f, 0.f, 0.f, 0.f);
        for (int r = 0; r < 64; ++r)
            for (int c = tid; c < nc4; c += 256)
                *(float4*)&weights[base + (size_t)r * SEQ + (size_t)c * 4] = z;
    }
}

// ---------------------------------------------------------------------------
// Kernel 3: output projection.  A:(BS,DIM) bf16, Wo:(DIM,DIM) fp32, + bias.
// ---------------------------------------------------------------------------
__global__ __launch_bounds__(256) void oproj_kernel(
    const bf16* __restrict__ A, const float* __restrict__ Wo,
    const float* __restrict__ bo, float* __restrict__ out)
{
    __shared__ float As[64][68];
    __shared__ float Ws[64][68];

    const int tid = threadIdx.x;
    const int tm = tid >> 4, tn = tid & 15;
    const int m0 = blockIdx.y * 64;
    const int n0 = blockIdx.x * 64;

    float acc[4][4] = {};

    for (int k0 = 0; k0 < DIM; k0 += 64) {
#pragma unroll
        for (int p = 0; p < 2; ++p) {
            int idx = tid + p * 256;
            int r = idx >> 3, c = (idx & 7) << 3;
            uint4 u = *(const uint4*)&A[(size_t)(m0 + r) * DIM + k0 + c];
            const bf16* hh = reinterpret_cast<const bf16*>(&u);
#pragma unroll
            for (int j = 0; j < 8; ++j) As[r][c + j] = __bfloat162float(hh[j]);
        }
#pragma unroll
        for (int p = 0; p < 4; ++p) {
            int idx = tid + p * 256;
            int r = idx >> 4, c = (idx & 15) << 2;
            *(float4*)&Ws[r][c] = *(const float4*)&Wo[(size_t)(n0 + r) * DIM + k0 + c];
        }
        __syncthreads();
        gemm_tile_64(As, Ws, tm, tn, acc);
        __syncthreads();
    }

#pragma unroll
    for (int i = 0; i < 4; ++i) {
        int m = m0 + tm * 4 + i;
#pragma unroll
        for (int j = 0; j < 4; ++j) {
            int n = n0 + tn + 16 * j;
            out[(size_t)m * DIM + n] = acc[i][j] + bo[n];
        }
    }
}

// ---------------------------------------------------------------------------
extern "C" void kernel_launch(void* const* d_in, const int* in_sizes, int n_in,
                              void* d_out, int out_size, void* d_ws, size_t ws_size,
                              hipStream_t stream)
{
    const float* Q  = (const float*)d_in[0];
    const float* K  = (const float*)d_in[1];
    const float* V  = (const float*)d_in[2];
    const float* Wq = (const float*)d_in[3];
    const float* Wk = (const float*)d_in[4];
    const float* Wv = (const float*)d_in[5];
    const float* Wo = (const float*)d_in[6];
    const float* bo = (const float*)d_in[7];

    float* out     = (float*)d_out;
    float* weights = out + (size_t)BS * DIM;   // second tuple output

    bf16* qws = (bf16*)d_ws;                   // (B,H,S,HDIM) bf16, 16 MB each
    bf16* kws = qws + (size_t)BS * DIM;
    bf16* vws = kws + (size_t)BS * DIM;
    bf16* aws = vws + (size_t)BS * DIM;        // attention out (B,S,DIM) bf16

    dim3 blk(256);
    proj_qkv_kernel<<<dim3(DIM / 64, BS / 64, 3), blk, 0, stream>>>(
        Q, K, V, Wq, Wk, Wv, qws, kws, vws);
    attn_kernel<<<dim3(SEQ / 64, HEADS, BATCH), blk, 0, stream>>>(
        qws, kws, vws, weights, aws);
    oproj_kernel<<<dim3(DIM / 64, BS / 64), blk, 0, stream>>>(
        aws, Wo, bo, out);
}

// Round 2
// 2179.008 us; speedup vs baseline: 2.4596x; 2.4596x over previous
//
#include <hip/hip_runtime.h>
#include <hip/hip_bf16.h>

typedef __hip_bfloat16 bf16;
typedef __attribute__((ext_vector_type(8))) short bf16x8;
typedef __attribute__((ext_vector_type(4))) float f32x4;

#define HEADS 16
#define HDIM  64
#define DIM   1024
#define SEQ   2048
#define BATCH 4
#define BS    (BATCH * SEQ)   // 8192
#define SCALE 0.125f          // 1/sqrt(64)

#define MFMA16(a, b, c) __builtin_amdgcn_mfma_f32_16x16x32_bf16(a, b, c, 0, 0, 0)

// ---------------------------------------------------------------------------
// fp32 VALU GEMM helpers (projection kernels — unchanged this round)
// ---------------------------------------------------------------------------
__device__ __forceinline__ void gemm_tile_64(const float (*As)[68], const float (*Bs)[68],
                                             int tm, int tn, float acc[4][4])
{
#pragma unroll
    for (int kk = 0; kk < 64; kk += 4) {
        float4 a[4], b[4];
#pragma unroll
        for (int i = 0; i < 4; ++i) a[i] = *(const float4*)&As[tm * 4 + i][kk];
#pragma unroll
        for (int j = 0; j < 4; ++j) b[j] = *(const float4*)&Bs[tn + 16 * j][kk];
#pragma unroll
        for (int i = 0; i < 4; ++i)
#pragma unroll
            for (int j = 0; j < 4; ++j)
                acc[i][j] += a[i].x * b[j].x + a[i].y * b[j].y
                           + a[i].z * b[j].z + a[i].w * b[j].w;
    }
}

// ---------------------------------------------------------------------------
// Kernel 1: QKV projections (fp32 VALU GEMM).  Q/K out: (B,H,S,D) bf16.
// V out: TRANSPOSED (B,H,D,S) bf16 so attention PV B-fragments are contiguous.
// ---------------------------------------------------------------------------
__global__ __launch_bounds__(256) void proj_qkv_kernel(
    const float* __restrict__ Qin, const float* __restrict__ Kin, const float* __restrict__ Vin,
    const float* __restrict__ Wq, const float* __restrict__ Wk, const float* __restrict__ Wv,
    bf16* __restrict__ qo, bf16* __restrict__ ko, bf16* __restrict__ vo)
{
    __shared__ float Xs[64][68];
    __shared__ float Ws[64][68];

    const float* X; const float* W; bf16* O;
    if (blockIdx.z == 0)      { X = Qin; W = Wq; O = qo; }
    else if (blockIdx.z == 1) { X = Kin; W = Wk; O = ko; }
    else                      { X = Vin; W = Wv; O = vo; }

    const int tid = threadIdx.x;
    const int tm = tid >> 4, tn = tid & 15;
    const int m0 = blockIdx.y * 64;
    const int n0 = blockIdx.x * 64;   // == head * 64

    float acc[4][4] = {};

    for (int k0 = 0; k0 < DIM; k0 += 64) {
#pragma unroll
        for (int p = 0; p < 4; ++p) {
            int idx = tid + p * 256;
            int r = idx >> 4, c = (idx & 15) << 2;
            *(float4*)&Xs[r][c] = *(const float4*)&X[(size_t)(m0 + r) * DIM + k0 + c];
            *(float4*)&Ws[r][c] = *(const float4*)&W[(size_t)(n0 + r) * DIM + k0 + c];
        }
        __syncthreads();
        gemm_tile_64(Xs, Ws, tm, tn, acc);
        __syncthreads();
    }

    const int h = blockIdx.x;
    if (blockIdx.z != 2) {
        // (B,H,S,D) layout
#pragma unroll
        for (int i = 0; i < 4; ++i) {
            int m = m0 + tm * 4 + i;
            int bb = m >> 11;          // / SEQ
            int ss = m & (SEQ - 1);
            size_t base = ((size_t)(bb * HEADS + h) * SEQ + ss) * HDIM;
#pragma unroll
            for (int j = 0; j < 4; ++j)
                O[base + tn + 16 * j] = __float2bfloat16(acc[i][j]);
        }
    } else {
        // V transposed: (B,H,D,S); 4 consecutive s per (d) -> 8B packed store
        int m_base = m0 + tm * 4;
        int bb = m_base >> 11, ss = m_base & (SEQ - 1);
        size_t row0 = (size_t)(bb * HEADS + h) * HDIM;
#pragma unroll
        for (int j = 0; j < 4; ++j) {
            union { bf16 hv[4]; uint2 u; } pk;
#pragma unroll
            for (int i = 0; i < 4; ++i) pk.hv[i] = __float2bfloat16(acc[i][j]);
            *(uint2*)&O[(row0 + tn + 16 * j) * SEQ + ss] = pk.u;
        }
    }
}

// ---------------------------------------------------------------------------
// Kernel 2: causal attention, MFMA bf16.
// Block = 256 thr (4 waves), one (b,h,64-row q-tile).  Wave w owns q rows
// [q0+16w, q0+16w+16).  K/V^T staged in LDS in fragment-linear layout
// (slot = lane -> conflict-free ds_read_b128).  Pass 1: online row stats in
// registers.  Pass 2: recompute QK^T, write normalized weights (NT stores),
// P -> wave-private LDS transpose -> PV MFMA.
// ---------------------------------------------------------------------------
__global__ __launch_bounds__(256) void attn_kernel(
    const bf16* __restrict__ qws, const bf16* __restrict__ kws, const bf16* __restrict__ vtws,
    float* __restrict__ weights, bf16* __restrict__ attn_out)
{
    __shared__ alignas(16) bf16 Ks[4096];   // ((ct*2+c)*64 + lane)*8
    __shared__ alignas(16) bf16 Vs[4096];   // ((td*2+kc)*64 + lane)*8
    __shared__ alignas(16) bf16 Ps[4096];   // ((wv*2+kc)*64 + slot)*8 (wave-private)

    const int tid  = threadIdx.x;
    const int lane = tid & 63;
    const int wave = tid >> 6;
    const int l15  = lane & 15;
    const int lg   = lane >> 4;
    const int qt = blockIdx.x;
    const int h  = blockIdx.y, b = blockIdx.z;
    const int bh = b * HEADS + h;
    const int q0 = qt * 64;

    const bf16* qbase = qws + (size_t)bh * SEQ * HDIM;
    const bf16* kbase = kws + (size_t)bh * SEQ * HDIM;
    const bf16* vbase = vtws + (size_t)bh * HDIM * SEQ;

    // Q fragments: A layout = row (lane&15), k = (lane>>4)*8 + e
    bf16x8 qa0, qa1;
    {
        const bf16* qp = qbase + (size_t)(q0 + 16 * wave + l15) * HDIM + lg * 8;
        qa0 = *(const bf16x8*)qp;
        qa1 = *(const bf16x8*)(qp + 32);
    }

#define LOADK(kt_, r0, r1) { \
    const bf16* rp = kbase + (size_t)((kt_) * 64 + 16 * wave + l15) * HDIM + lg * 8; \
    r0 = *(const uint4*)rp; r1 = *(const uint4*)(rp + 32); }
#define STOREK(r0, r1) { \
    *(uint4*)&Ks[((wave * 2 + 0) * 64 + lane) * 8] = r0; \
    *(uint4*)&Ks[((wave * 2 + 1) * 64 + lane) * 8] = r1; }
#define LOADV(kt_, r0, r1) { \
    const bf16* rp = vbase + (size_t)(16 * wave + l15) * SEQ + (kt_) * 64 + lg * 8; \
    r0 = *(const uint4*)rp; r1 = *(const uint4*)(rp + 32); }
#define STOREV(r0, r1) { \
    *(uint4*)&Vs[((wave * 2 + 0) * 64 + lane) * 8] = r0; \
    *(uint4*)&Vs[((wave * 2 + 1) * 64 + lane) * 8] = r1; }
#define QKT(acc_) { \
    _Pragma("unroll") \
    for (int ct = 0; ct < 4; ++ct) { \
        bf16x8 b0 = *(const bf16x8*)&Ks[((ct * 2 + 0) * 64 + lane) * 8]; \
        bf16x8 b1 = *(const bf16x8*)&Ks[((ct * 2 + 1) * 64 + lane) * 8]; \
        acc_[ct] = MFMA16(qa0, b0, acc_[ct]); \
        acc_[ct] = MFMA16(qa1, b1, acc_[ct]); \
    } }

    // ---- pass 1: online row max / sum-exp (register-resident stats) ----
    float m_run[4] = {-1e30f, -1e30f, -1e30f, -1e30f};
    float l_run[4] = {0.f, 0.f, 0.f, 0.f};

    {
        uint4 k0, k1;
        LOADK(0, k0, k1);
        STOREK(k0, k1);
    }
    for (int kt = 0; kt <= qt; ++kt) {
        __syncthreads();                      // staged K ready
        f32x4 acc[4] = {};
        QKT(acc);
        const bool more = kt < qt;
        uint4 nk0, nk1;
        if (more) LOADK(kt + 1, nk0, nk1);    // overlap with stats
        const bool diag = (kt == qt);
#pragma unroll
        for (int r = 0; r < 4; ++r) {
            float s0 = acc[0][r] * SCALE;
            float s1 = acc[1][r] * SCALE;
            float s2 = acc[2][r] * SCALE;
            float s3 = acc[3][r] * SCALE;
            if (diag) {
                int rr = 16 * wave + lg * 4 + r;
                if (l15      > rr) s0 = -1e30f;
                if (l15 + 16 > rr) s1 = -1e30f;
                if (l15 + 32 > rr) s2 = -1e30f;
                if (l15 + 48 > rr) s3 = -1e30f;
            }
            float t = fmaxf(fmaxf(s0, s1), fmaxf(s2, s3));
            t = fmaxf(t, __shfl_xor(t, 1));
            t = fmaxf(t, __shfl_xor(t, 2));
            t = fmaxf(t, __shfl_xor(t, 4));
            t = fmaxf(t, __shfl_xor(t, 8));
            float mn = fmaxf(m_run[r], t);
            float ps = __expf(s0 - mn) + __expf(s1 - mn)
                     + __expf(s2 - mn) + __expf(s3 - mn);
            ps += __shfl_xor(ps, 1);
            ps += __shfl_xor(ps, 2);
            ps += __shfl_xor(ps, 4);
            ps += __shfl_xor(ps, 8);
            l_run[r] = l_run[r] * __expf(m_run[r] - mn) + ps;
            m_run[r] = mn;
        }
        __syncthreads();                      // all waves done reading Ks
        if (more) STOREK(nk0, nk1);
    }

    float il[4];
#pragma unroll
    for (int r = 0; r < 4; ++r) il[r] = 1.0f / l_run[r];

    // ---- pass 2: weights + PV ----
    {
        uint4 k0, k1, v0, v1;
        LOADK(0, k0, k1);
        LOADV(0, v0, v1);
        STOREK(k0, k1);
        STOREV(v0, v1);
    }
    f32x4 oacc[4] = {};
    size_t wbase[4];
#pragma unroll
    for (int r = 0; r < 4; ++r)
        wbase[r] = ((size_t)bh * SEQ + (q0 + 16 * wave + lg * 4 + r)) * SEQ;

    for (int kt = 0; kt <= qt; ++kt) {
        __syncthreads();                      // staged K,V ready
        f32x4 acc[4] = {};
        QKT(acc);
        const bool more = kt < qt;
        uint4 nk0, nk1, nv0, nv1;
        if (more) { LOADK(kt + 1, nk0, nk1); LOADV(kt + 1, nv0, nv1); }
        const bool diag = (kt == qt);
#pragma unroll
        for (int ct = 0; ct < 4; ++ct) {
#pragma unroll
            for (int r = 0; r < 4; ++r) {
                float s = acc[ct][r] * SCALE;
                if (diag && (ct * 16 + l15 > 16 * wave + lg * 4 + r)) s = -1e30f;
                float w = __expf(s - m_run[r]) * il[r];
                __builtin_nontemporal_store(
                    w, &weights[wbase[r] + kt * 64 + ct * 16 + l15]);
                // P transpose into wave-private LDS (A-fragment layout)
                Ps[((wave * 2 + (ct >> 1)) * 64
                    + (lg * 4 + r) + 16 * ((ct & 1) * 2 + (l15 >> 3))) * 8
                   + (l15 & 7)] = __float2bfloat16(w);
            }
        }
        // PV: Ps is wave-private; compiler orders ds_write -> ds_read.
        bf16x8 pa0 = *(const bf16x8*)&Ps[((wave * 2 + 0) * 64 + lane) * 8];
        bf16x8 pa1 = *(const bf16x8*)&Ps[((wave * 2 + 1) * 64 + lane) * 8];
#pragma unroll
        for (int td = 0; td < 4; ++td) {
            bf16x8 vb0 = *(const bf16x8*)&Vs[((td * 2 + 0) * 64 + lane) * 8];
            bf16x8 vb1 = *(const bf16x8*)&Vs[((td * 2 + 1) * 64 + lane) * 8];
            oacc[td] = MFMA16(pa0, vb0, oacc[td]);
            oacc[td] = MFMA16(pa1, vb1, oacc[td]);
        }
        __syncthreads();                      // all waves done with Ks/Vs
        if (more) { STOREK(nk0, nk1); STOREV(nv0, nv1); }
    }

    // O tile write: (b, s, h*64 + d) bf16
#pragma unroll
    for (int td = 0; td < 4; ++td)
#pragma unroll
        for (int r = 0; r < 4; ++r) {
            int rowg = q0 + 16 * wave + lg * 4 + r;
            attn_out[((size_t)b * SEQ + rowg) * DIM + h * HDIM + td * 16 + l15]
                = __float2bfloat16(oacc[td][r]);
        }

    // zero-fill masked (upper-triangle) weight columns (streaming NT stores)
    const int zc0 = (qt + 1) * 64;
    if (zc0 < SEQ) {
        const int nc4 = (SEQ - zc0) >> 2;
        const size_t base = ((size_t)bh * SEQ + q0) * SEQ + zc0;
        const f32x4 z = {0.f, 0.f, 0.f, 0.f};
        for (int r = 0; r < 64; ++r)
            for (int c = tid; c < nc4; c += 256)
                __builtin_nontemporal_store(
                    z, (f32x4*)&weights[base + (size_t)r * SEQ + (size_t)c * 4]);
    }
#undef LOADK
#undef STOREK
#undef LOADV
#undef STOREV
#undef QKT
}

// ---------------------------------------------------------------------------
// Kernel 3: output projection (fp32 VALU GEMM, unchanged).
// ---------------------------------------------------------------------------
__global__ __launch_bounds__(256) void oproj_kernel(
    const bf16* __restrict__ A, const float* __restrict__ Wo,
    const float* __restrict__ bo, float* __restrict__ out)
{
    __shared__ float As[64][68];
    __shared__ float Ws[64][68];

    const int tid = threadIdx.x;
    const int tm = tid >> 4, tn = tid & 15;
    const int m0 = blockIdx.y * 64;
    const int n0 = blockIdx.x * 64;

    float acc[4][4] = {};

    for (int k0 = 0; k0 < DIM; k0 += 64) {
#pragma unroll
        for (int p = 0; p < 2; ++p) {
            int idx = tid + p * 256;
            int r = idx >> 3, c = (idx & 7) << 3;
            uint4 u = *(const uint4*)&A[(size_t)(m0 + r) * DIM + k0 + c];
            const bf16* hh = reinterpret_cast<const bf16*>(&u);
#pragma unroll
            for (int j = 0; j < 8; ++j) As[r][c + j] = __bfloat162float(hh[j]);
        }
#pragma unroll
        for (int p = 0; p < 4; ++p) {
            int idx = tid + p * 256;
            int r = idx >> 4, c = (idx & 15) << 2;
            *(float4*)&Ws[r][c] = *(const float4*)&Wo[(size_t)(n0 + r) * DIM + k0 + c];
        }
        __syncthreads();
        gemm_tile_64(As, Ws, tm, tn, acc);
        __syncthreads();
    }

#pragma unroll
    for (int i = 0; i < 4; ++i) {
        int m = m0 + tm * 4 + i;
#pragma unroll
        for (int j = 0; j < 4; ++j) {
            int n = n0 + tn + 16 * j;
            out[(size_t)m * DIM + n] = acc[i][j] + bo[n];
        }
    }
}

// ---------------------------------------------------------------------------
extern "C" void kernel_launch(void* const* d_in, const int* in_sizes, int n_in,
                              void* d_out, int out_size, void* d_ws, size_t ws_size,
                              hipStream_t stream)
{
    const float* Q  = (const float*)d_in[0];
    const float* K  = (const float*)d_in[1];
    const float* V  = (const float*)d_in[2];
    const float* Wq = (const float*)d_in[3];
    const float* Wk = (const float*)d_in[4];
    const float* Wv = (const float*)d_in[5];
    const float* Wo = (const float*)d_in[6];
    const float* bo = (const float*)d_in[7];

    float* out     = (float*)d_out;
    float* weights = out + (size_t)BS * DIM;   // second tuple output

    bf16* qws  = (bf16*)d_ws;                  // (B,H,S,D)  bf16
    bf16* kws  = qws + (size_t)BS * DIM;       // (B,H,S,D)  bf16
    bf16* vtws = kws + (size_t)BS * DIM;       // (B,H,D,S)  bf16 (transposed)
    bf16* aws  = vtws + (size_t)BS * DIM;      // (B,S,DIM)  bf16

    dim3 blk(256);
    proj_qkv_kernel<<<dim3(DIM / 64, BS / 64, 3), blk, 0, stream>>>(
        Q, K, V, Wq, Wk, Wv, qws, kws, vtws);
    attn_kernel<<<dim3(SEQ / 64, HEADS, BATCH), blk, 0, stream>>>(
        qws, kws, vtws, weights, aws);
    oproj_kernel<<<dim3(DIM / 64, BS / 64), blk, 0, stream>>>(
        aws, Wo, bo, out);
}

// Round 4
// 504.511 us; speedup vs baseline: 10.6233x; 4.3191x over previous
//
#include <hip/hip_runtime.h>
#include <hip/hip_bf16.h>

typedef __hip_bfloat16 bf16;
typedef __attribute__((ext_vector_type(8))) short bf16x8;
typedef __attribute__((ext_vector_type(4))) float f32x4;

#define HEADS 16
#define HDIM  64
#define DIM   1024
#define SEQ   2048
#define BATCH 4
#define BS    (BATCH * SEQ)   // 8192
#define SCALE 0.125f          // 1/sqrt(64)

#define MFMA16(a, b, c) __builtin_amdgcn_mfma_f32_16x16x32_bf16(a, b, c, 0, 0, 0)

__device__ __forceinline__ void gload_lds16(const void* g, void* l) {
    __builtin_amdgcn_global_load_lds(
        (const __attribute__((address_space(1))) void*)g,
        (__attribute__((address_space(3))) void*)l, 16, 0, 0);
}

__device__ __forceinline__ void cvt8(const float* __restrict__ src, bf16* __restrict__ dst,
                                     size_t i)
{
    float4 f0 = *(const float4*)&src[i];
    float4 f1 = *(const float4*)&src[i + 4];
    union { bf16 h[8]; uint4 u; } pk;
    pk.h[0] = __float2bfloat16(f0.x); pk.h[1] = __float2bfloat16(f0.y);
    pk.h[2] = __float2bfloat16(f0.z); pk.h[3] = __float2bfloat16(f0.w);
    pk.h[4] = __float2bfloat16(f1.x); pk.h[5] = __float2bfloat16(f1.y);
    pk.h[6] = __float2bfloat16(f1.z); pk.h[7] = __float2bfloat16(f1.w);
    *(uint4*)&dst[i] = pk.u;
}

// ---------------------------------------------------------------------------
// Kernel 0a: fp32 -> bf16 for Q,K,V,Wq,Wk,Wv (all consumed by proj, which
// completes BEFORE attn overwrites the scratch region).
// ---------------------------------------------------------------------------
__global__ __launch_bounds__(256) void cvt_kernel(
    const float* __restrict__ Q, const float* __restrict__ K, const float* __restrict__ V,
    const float* __restrict__ Wq, const float* __restrict__ Wk, const float* __restrict__ Wv,
    bf16* __restrict__ xq, bf16* __restrict__ xk, bf16* __restrict__ xv,
    bf16* __restrict__ wq, bf16* __restrict__ wk, bf16* __restrict__ wv)
{
    const int seg = blockIdx.y;
    const float* src; bf16* dst; size_t n;
    switch (seg) {
        case 0: src = Q;  dst = xq; n = (size_t)BS * DIM;   break;
        case 1: src = K;  dst = xk; n = (size_t)BS * DIM;   break;
        case 2: src = V;  dst = xv; n = (size_t)BS * DIM;   break;
        case 3: src = Wq; dst = wq; n = (size_t)DIM * DIM;  break;
        case 4: src = Wk; dst = wk; n = (size_t)DIM * DIM;  break;
        default: src = Wv; dst = wv; n = (size_t)DIM * DIM; break;
    }
    size_t i = ((size_t)blockIdx.x * 256 + threadIdx.x) * 8;
    if (i >= n) return;
    cvt8(src, dst, i);
}

// Kernel 0b: Wo fp32 -> bf16, launched AFTER attn into the then-dead qws
// region of d_ws (attn is qws's last reader).
__global__ __launch_bounds__(256) void cvt_wo_kernel(
    const float* __restrict__ Wo, bf16* __restrict__ wo)
{
    size_t i = ((size_t)blockIdx.x * 256 + threadIdx.x) * 8;
    cvt8(Wo, wo, i);
}

// ---------------------------------------------------------------------------
// MFMA GEMM core: 128x128 C-tile of A (row-major, ld=DIM) x B^T (B row-major,
// ld=DIM), K=DIM.  4 waves; wave (wr,wc) owns a 64x64 sub-tile.
// LDS is fragment-linear: chunk c (=frag-group*2+kslice) at sA/sB + c*512
// bf16; lane l holds row (c>>1)*16 + (l&15), k = (c&1)*32 + (l>>4)*8 — the
// exact mfma_16x16x32 A/B fragment layout.  Staged with global_load_lds
// (linear LDS dest = base + lane*16B; fragment mapping carried by the
// per-lane GLOBAL address).  ds_read_b128 reads are lane-linear -> uniform
// 8 lanes per 16B bank-slot = b128 throughput floor, no conflicts.
// ---------------------------------------------------------------------------
__device__ __forceinline__ void mfma_core_1024(
    const bf16* __restrict__ A, const bf16* __restrict__ B,
    int m0, int n0, bf16* sA, f32x4 acc[4][4])
{
    const int tid = threadIdx.x, lane = tid & 63, wave = tid >> 6;
    const int l15 = lane & 15, lg = lane >> 4;
    const int wr = wave >> 1, wc = wave & 1;
    bf16* sB = sA + 16 * 512;

    const bf16* gsrc = (wave < 2) ? A : B;
    const int   gm0  = (wave < 2) ? m0 : n0;
    bf16*       sdst = (wave < 2) ? sA : sB;
    const int   wv2  = wave & 1;          // which 8 chunks this wave stages

#define STAGE(k0_) { \
    _Pragma("unroll") for (int u = 0; u < 8; ++u) { \
        const int c = wv2 * 8 + u; \
        const int mg = c >> 1, s = c & 1; \
        gload_lds16(gsrc + (size_t)(gm0 + mg * 16 + l15) * DIM + (k0_) + s * 32 + lg * 8, \
                    sdst + c * 512); \
    } }

    STAGE(0);
#pragma unroll 1
    for (int t = 0; t < DIM / 64; ++t) {
        __syncthreads();                  // vmcnt drain: staged tile ready
#pragma unroll
        for (int s = 0; s < 2; ++s) {
            bf16x8 af[4], bfr[4];
#pragma unroll
            for (int i = 0; i < 4; ++i)
                af[i] = *(const bf16x8*)(sA + ((wr * 4 + i) * 2 + s) * 512 + lane * 8);
#pragma unroll
            for (int j = 0; j < 4; ++j)
                bfr[j] = *(const bf16x8*)(sB + ((wc * 4 + j) * 2 + s) * 512 + lane * 8);
#pragma unroll
            for (int i = 0; i < 4; ++i)
#pragma unroll
                for (int j = 0; j < 4; ++j)
                    acc[i][j] = MFMA16(af[i], bfr[j], acc[i][j]);
        }
        __syncthreads();                  // all waves done reading
        if (t < DIM / 64 - 1) STAGE((t + 1) * 64);
    }
#undef STAGE
}

// ---------------------------------------------------------------------------
// Kernel 1: QKV projections via MFMA.  Q/K out (B,H,S,D); V out (B,H,D,S).
// ---------------------------------------------------------------------------
__global__ __launch_bounds__(256) void proj_mfma_kernel(
    const bf16* __restrict__ Xq, const bf16* __restrict__ Xk, const bf16* __restrict__ Xv,
    const bf16* __restrict__ Wq, const bf16* __restrict__ Wk, const bf16* __restrict__ Wv,
    bf16* __restrict__ qo, bf16* __restrict__ ko, bf16* __restrict__ vo)
{
    __shared__ alignas(16) bf16 smem[16384];   // 32 KB
    const int z = blockIdx.z;
    const bf16* X = z == 0 ? Xq : z == 1 ? Xk : Xv;
    const bf16* W = z == 0 ? Wq : z == 1 ? Wk : Wv;
    const int m0 = blockIdx.y * 128, n0 = blockIdx.x * 128;
    f32x4 acc[4][4] = {};
    mfma_core_1024(X, W, m0, n0, smem, acc);

    const int tid = threadIdx.x, lane = tid & 63, wave = tid >> 6;
    const int l15 = lane & 15, lg = lane >> 4, wr = wave >> 1, wc = wave & 1;
    const int h = blockIdx.x * 2 + wc;     // 128-wide n-tile spans 2 heads

    if (z != 2) {
        bf16* O = z == 0 ? qo : ko;
#pragma unroll
        for (int i = 0; i < 4; ++i)
#pragma unroll
            for (int r = 0; r < 4; ++r) {
                int m = m0 + wr * 64 + i * 16 + lg * 4 + r;
                int bb = m >> 11, ss = m & (SEQ - 1);
                size_t base = ((size_t)(bb * HEADS + h) * SEQ + ss) * HDIM;
#pragma unroll
                for (int j = 0; j < 4; ++j)
                    O[base + j * 16 + l15] = __float2bfloat16(acc[i][j][r]);
            }
    } else {
        // V transposed: (B,H,D,S); r=0..3 are consecutive s -> 8B packed store
#pragma unroll
        for (int i = 0; i < 4; ++i) {
            int s0 = m0 + wr * 64 + i * 16 + lg * 4;
            int bb = s0 >> 11, ss = s0 & (SEQ - 1);
#pragma unroll
            for (int j = 0; j < 4; ++j) {
                int d = j * 16 + l15;
                union { bf16 h4[4]; uint2 u; } pk;
#pragma unroll
                for (int r = 0; r < 4; ++r) pk.h4[r] = __float2bfloat16(acc[i][j][r]);
                *(uint2*)&vo[((size_t)(bb * HEADS + h) * HDIM + d) * SEQ + ss] = pk.u;
            }
        }
    }
}

// ---------------------------------------------------------------------------
// Kernel 2: causal attention, MFMA bf16 (unchanged from round 2).
// ---------------------------------------------------------------------------
__global__ __launch_bounds__(256) void attn_kernel(
    const bf16* __restrict__ qws, const bf16* __restrict__ kws, const bf16* __restrict__ vtws,
    float* __restrict__ weights, bf16* __restrict__ attn_out)
{
    __shared__ alignas(16) bf16 Ks[4096];
    __shared__ alignas(16) bf16 Vs[4096];
    __shared__ alignas(16) bf16 Ps[4096];

    const int tid  = threadIdx.x;
    const int lane = tid & 63;
    const int wave = tid >> 6;
    const int l15  = lane & 15;
    const int lg   = lane >> 4;
    const int qt = blockIdx.x;
    const int h  = blockIdx.y, b = blockIdx.z;
    const int bh = b * HEADS + h;
    const int q0 = qt * 64;

    const bf16* qbase = qws + (size_t)bh * SEQ * HDIM;
    const bf16* kbase = kws + (size_t)bh * SEQ * HDIM;
    const bf16* vbase = vtws + (size_t)bh * HDIM * SEQ;

    bf16x8 qa0, qa1;
    {
        const bf16* qp = qbase + (size_t)(q0 + 16 * wave + l15) * HDIM + lg * 8;
        qa0 = *(const bf16x8*)qp;
        qa1 = *(const bf16x8*)(qp + 32);
    }

#define LOADK(kt_, r0, r1) { \
    const bf16* rp = kbase + (size_t)((kt_) * 64 + 16 * wave + l15) * HDIM + lg * 8; \
    r0 = *(const uint4*)rp; r1 = *(const uint4*)(rp + 32); }
#define STOREK(r0, r1) { \
    *(uint4*)&Ks[((wave * 2 + 0) * 64 + lane) * 8] = r0; \
    *(uint4*)&Ks[((wave * 2 + 1) * 64 + lane) * 8] = r1; }
#define LOADV(kt_, r0, r1) { \
    const bf16* rp = vbase + (size_t)(16 * wave + l15) * SEQ + (kt_) * 64 + lg * 8; \
    r0 = *(const uint4*)rp; r1 = *(const uint4*)(rp + 32); }
#define STOREV(r0, r1) { \
    *(uint4*)&Vs[((wave * 2 + 0) * 64 + lane) * 8] = r0; \
    *(uint4*)&Vs[((wave * 2 + 1) * 64 + lane) * 8] = r1; }
#define QKT(acc_) { \
    _Pragma("unroll") \
    for (int ct = 0; ct < 4; ++ct) { \
        bf16x8 b0 = *(const bf16x8*)&Ks[((ct * 2 + 0) * 64 + lane) * 8]; \
        bf16x8 b1 = *(const bf16x8*)&Ks[((ct * 2 + 1) * 64 + lane) * 8]; \
        acc_[ct] = MFMA16(qa0, b0, acc_[ct]); \
        acc_[ct] = MFMA16(qa1, b1, acc_[ct]); \
    } }

    float m_run[4] = {-1e30f, -1e30f, -1e30f, -1e30f};
    float l_run[4] = {0.f, 0.f, 0.f, 0.f};

    {
        uint4 k0, k1;
        LOADK(0, k0, k1);
        STOREK(k0, k1);
    }
    for (int kt = 0; kt <= qt; ++kt) {
        __syncthreads();
        f32x4 acc[4] = {};
        QKT(acc);
        const bool more = kt < qt;
        uint4 nk0, nk1;
        if (more) LOADK(kt + 1, nk0, nk1);
        const bool diag = (kt == qt);
#pragma unroll
        for (int r = 0; r < 4; ++r) {
            float s0 = acc[0][r] * SCALE;
            float s1 = acc[1][r] * SCALE;
            float s2 = acc[2][r] * SCALE;
            float s3 = acc[3][r] * SCALE;
            if (diag) {
                int rr = 16 * wave + lg * 4 + r;
                if (l15      > rr) s0 = -1e30f;
                if (l15 + 16 > rr) s1 = -1e30f;
                if (l15 + 32 > rr) s2 = -1e30f;
                if (l15 + 48 > rr) s3 = -1e30f;
            }
            float t = fmaxf(fmaxf(s0, s1), fmaxf(s2, s3));
            t = fmaxf(t, __shfl_xor(t, 1));
            t = fmaxf(t, __shfl_xor(t, 2));
            t = fmaxf(t, __shfl_xor(t, 4));
            t = fmaxf(t, __shfl_xor(t, 8));
            float mn = fmaxf(m_run[r], t);
            float ps = __expf(s0 - mn) + __expf(s1 - mn)
                     + __expf(s2 - mn) + __expf(s3 - mn);
            ps += __shfl_xor(ps, 1);
            ps += __shfl_xor(ps, 2);
            ps += __shfl_xor(ps, 4);
            ps += __shfl_xor(ps, 8);
            l_run[r] = l_run[r] * __expf(m_run[r] - mn) + ps;
            m_run[r] = mn;
        }
        __syncthreads();
        if (more) STOREK(nk0, nk1);
    }

    float il[4];
#pragma unroll
    for (int r = 0; r < 4; ++r) il[r] = 1.0f / l_run[r];

    {
        uint4 k0, k1, v0, v1;
        LOADK(0, k0, k1);
        LOADV(0, v0, v1);
        STOREK(k0, k1);
        STOREV(v0, v1);
    }
    f32x4 oacc[4] = {};
    size_t wbase[4];
#pragma unroll
    for (int r = 0; r < 4; ++r)
        wbase[r] = ((size_t)bh * SEQ + (q0 + 16 * wave + lg * 4 + r)) * SEQ;

    for (int kt = 0; kt <= qt; ++kt) {
        __syncthreads();
        f32x4 acc[4] = {};
        QKT(acc);
        const bool more = kt < qt;
        uint4 nk0, nk1, nv0, nv1;
        if (more) { LOADK(kt + 1, nk0, nk1); LOADV(kt + 1, nv0, nv1); }
        const bool diag = (kt == qt);
#pragma unroll
        for (int ct = 0; ct < 4; ++ct) {
#pragma unroll
            for (int r = 0; r < 4; ++r) {
                float s = acc[ct][r] * SCALE;
                if (diag && (ct * 16 + l15 > 16 * wave + lg * 4 + r)) s = -1e30f;
                float w = __expf(s - m_run[r]) * il[r];
                __builtin_nontemporal_store(
                    w, &weights[wbase[r] + kt * 64 + ct * 16 + l15]);
                Ps[((wave * 2 + (ct >> 1)) * 64
                    + (lg * 4 + r) + 16 * ((ct & 1) * 2 + (l15 >> 3))) * 8
                   + (l15 & 7)] = __float2bfloat16(w);
            }
        }
        bf16x8 pa0 = *(const bf16x8*)&Ps[((wave * 2 + 0) * 64 + lane) * 8];
        bf16x8 pa1 = *(const bf16x8*)&Ps[((wave * 2 + 1) * 64 + lane) * 8];
#pragma unroll
        for (int td = 0; td < 4; ++td) {
            bf16x8 vb0 = *(const bf16x8*)&Vs[((td * 2 + 0) * 64 + lane) * 8];
            bf16x8 vb1 = *(const bf16x8*)&Vs[((td * 2 + 1) * 64 + lane) * 8];
            oacc[td] = MFMA16(pa0, vb0, oacc[td]);
            oacc[td] = MFMA16(pa1, vb1, oacc[td]);
        }
        __syncthreads();
        if (more) { STOREK(nk0, nk1); STOREV(nv0, nv1); }
    }

#pragma unroll
    for (int td = 0; td < 4; ++td)
#pragma unroll
        for (int r = 0; r < 4; ++r) {
            int rowg = q0 + 16 * wave + lg * 4 + r;
            attn_out[((size_t)b * SEQ + rowg) * DIM + h * HDIM + td * 16 + l15]
                = __float2bfloat16(oacc[td][r]);
        }

    const int zc0 = (qt + 1) * 64;
    if (zc0 < SEQ) {
        const int nc4 = (SEQ - zc0) >> 2;
        const size_t base = ((size_t)bh * SEQ + q0) * SEQ + zc0;
        const f32x4 z = {0.f, 0.f, 0.f, 0.f};
        for (int r = 0; r < 64; ++r)
            for (int c = tid; c < nc4; c += 256)
                __builtin_nontemporal_store(
                    z, (f32x4*)&weights[base + (size_t)r * SEQ + (size_t)c * 4]);
    }
#undef LOADK
#undef STOREK
#undef LOADV
#undef STOREV
#undef QKT
}

// ---------------------------------------------------------------------------
// Kernel 3: output projection via MFMA, fp32 out + bias.
// ---------------------------------------------------------------------------
__global__ __launch_bounds__(256) void oproj_mfma_kernel(
    const bf16* __restrict__ A, const bf16* __restrict__ Wo,
    const float* __restrict__ bo, float* __restrict__ out)
{
    __shared__ alignas(16) bf16 smem[16384];
    const int m0 = blockIdx.y * 128, n0 = blockIdx.x * 128;
    f32x4 acc[4][4] = {};
    mfma_core_1024(A, Wo, m0, n0, smem, acc);

    const int tid = threadIdx.x, lane = tid & 63, wave = tid >> 6;
    const int l15 = lane & 15, lg = lane >> 4, wr = wave >> 1, wc = wave & 1;
    float bv[4];
#pragma unroll
    for (int j = 0; j < 4; ++j) bv[j] = bo[n0 + wc * 64 + j * 16 + l15];
#pragma unroll
    for (int i = 0; i < 4; ++i)
#pragma unroll
        for (int r = 0; r < 4; ++r) {
            int m = m0 + wr * 64 + i * 16 + lg * 4 + r;
#pragma unroll
            for (int j = 0; j < 4; ++j)
                out[(size_t)m * DIM + n0 + wc * 64 + j * 16 + l15] = acc[i][j][r] + bv[j];
        }
}

// ---------------------------------------------------------------------------
extern "C" void kernel_launch(void* const* d_in, const int* in_sizes, int n_in,
                              void* d_out, int out_size, void* d_ws, size_t ws_size,
                              hipStream_t stream)
{
    const float* Q  = (const float*)d_in[0];
    const float* K  = (const float*)d_in[1];
    const float* V  = (const float*)d_in[2];
    const float* Wq = (const float*)d_in[3];
    const float* Wk = (const float*)d_in[4];
    const float* Wv = (const float*)d_in[5];
    const float* Wo = (const float*)d_in[6];
    const float* bo = (const float*)d_in[7];

    float* out     = (float*)d_out;
    float* weights = out + (size_t)BS * DIM;   // 268,435,456 floats

    // Pre-attn bf16 scratch lives in the TAIL of the weights buffer; its only
    // readers (proj_mfma) complete before attn overwrites all of weights.
    const size_t XN = (size_t)BS * DIM;        // 8,388,608
    const size_t WN = (size_t)DIM * DIM;       // 1,048,576
    const size_t scratch_elems = 3 * XN + 3 * WN;   // bf16 elements
    bf16* cvt = (bf16*)(weights + ((size_t)268435456 - scratch_elems / 2));
    bf16* xq  = cvt;
    bf16* xk  = xq + XN;
    bf16* xv  = xk + XN;
    bf16* wqc = xv + XN;
    bf16* wkc = wqc + WN;
    bf16* wvc = wkc + WN;

    bf16* qws  = (bf16*)d_ws;                  // (B,H,S,D)  bf16
    bf16* kws  = qws + (size_t)BS * DIM;       // (B,H,S,D)  bf16
    bf16* vtws = kws + (size_t)BS * DIM;       // (B,H,D,S)  bf16 (transposed)
    bf16* aws  = vtws + (size_t)BS * DIM;      // (B,S,DIM)  bf16
    bf16* woc  = qws;                          // reuse qws region AFTER attn

    dim3 blk(256);
    cvt_kernel<<<dim3(4096, 6), blk, 0, stream>>>(
        Q, K, V, Wq, Wk, Wv, xq, xk, xv, wqc, wkc, wvc);
    proj_mfma_kernel<<<dim3(DIM / 128, BS / 128, 3), blk, 0, stream>>>(
        xq, xk, xv, wqc, wkc, wvc, qws, kws, vtws);
    attn_kernel<<<dim3(SEQ / 64, HEADS, BATCH), blk, 0, stream>>>(
        qws, kws, vtws, weights, aws);
    // Wo conversion AFTER attn: qws region is dead by now (attn was its last
    // reader), so it is safe scratch for oproj's bf16 weight matrix.
    cvt_wo_kernel<<<dim3(WN / (256 * 8)), blk, 0, stream>>>(Wo, woc);
    oproj_mfma_kernel<<<dim3(DIM / 128, BS / 128), blk, 0, stream>>>(
        aws, woc, bo, out);
}

// Round 6
// 483.983 us; speedup vs baseline: 11.0738x; 1.0424x over previous
//
#include <hip/hip_runtime.h>
#include <hip/hip_bf16.h>

typedef __hip_bfloat16 bf16;
typedef __attribute__((ext_vector_type(8))) short bf16x8;
typedef __attribute__((ext_vector_type(4))) float f32x4;

#define HEADS 16
#define HDIM  64
#define DIM   1024
#define SEQ   2048
#define BATCH 4
#define BS    (BATCH * SEQ)   // 8192
#define SCALE 0.125f          // 1/sqrt(64)
#define CS    0.1803368801111f  // SCALE * log2(e): softmax in exp2 domain

#define EXP2F(x) __builtin_amdgcn_exp2f(x)
#define MFMA16(a, b, c) __builtin_amdgcn_mfma_f32_16x16x32_bf16(a, b, c, 0, 0, 0)

__device__ __forceinline__ void gload_lds16(const void* g, void* l) {
    __builtin_amdgcn_global_load_lds(
        (const __attribute__((address_space(1))) void*)g,
        (__attribute__((address_space(3))) void*)l, 16, 0, 0);
}

__device__ __forceinline__ void cvt8(const float* __restrict__ src, bf16* __restrict__ dst,
                                     size_t i)
{
    float4 f0 = *(const float4*)&src[i];
    float4 f1 = *(const float4*)&src[i + 4];
    union { bf16 h[8]; uint4 u; } pk;
    pk.h[0] = __float2bfloat16(f0.x); pk.h[1] = __float2bfloat16(f0.y);
    pk.h[2] = __float2bfloat16(f0.z); pk.h[3] = __float2bfloat16(f0.w);
    pk.h[4] = __float2bfloat16(f1.x); pk.h[5] = __float2bfloat16(f1.y);
    pk.h[6] = __float2bfloat16(f1.z); pk.h[7] = __float2bfloat16(f1.w);
    *(uint4*)&dst[i] = pk.u;
}

// ---------------------------------------------------------------------------
// Kernel 0a: fp32 -> bf16 for Q,K,V,Wq,Wk,Wv (consumed by proj, which
// completes BEFORE attn overwrites the scratch region in weights-tail).
// ---------------------------------------------------------------------------
__global__ __launch_bounds__(256) void cvt_kernel(
    const float* __restrict__ Q, const float* __restrict__ K, const float* __restrict__ V,
    const float* __restrict__ Wq, const float* __restrict__ Wk, const float* __restrict__ Wv,
    bf16* __restrict__ xq, bf16* __restrict__ xk, bf16* __restrict__ xv,
    bf16* __restrict__ wq, bf16* __restrict__ wk, bf16* __restrict__ wv)
{
    const int seg = blockIdx.y;
    const float* src; bf16* dst; size_t n;
    switch (seg) {
        case 0: src = Q;  dst = xq; n = (size_t)BS * DIM;   break;
        case 1: src = K;  dst = xk; n = (size_t)BS * DIM;   break;
        case 2: src = V;  dst = xv; n = (size_t)BS * DIM;   break;
        case 3: src = Wq; dst = wq; n = (size_t)DIM * DIM;  break;
        case 4: src = Wk; dst = wk; n = (size_t)DIM * DIM;  break;
        default: src = Wv; dst = wv; n = (size_t)DIM * DIM; break;
    }
    size_t i = ((size_t)blockIdx.x * 256 + threadIdx.x) * 8;
    if (i >= n) return;
    cvt8(src, dst, i);
}

// Kernel 0b: Wo fp32 -> bf16, launched AFTER attn into the then-dead qws
// region of d_ws (attn is qws's last reader).
__global__ __launch_bounds__(256) void cvt_wo_kernel(
    const float* __restrict__ Wo, bf16* __restrict__ wo)
{
    size_t i = ((size_t)blockIdx.x * 256 + threadIdx.x) * 8;
    cvt8(Wo, wo, i);
}

// ---------------------------------------------------------------------------
// MFMA GEMM core: 128x128 C-tile of A (row-major, ld=DIM) x B^T (B row-major,
// ld=DIM), K=DIM.  Fragment-linear LDS (see round-2 comment).
// ---------------------------------------------------------------------------
__device__ __forceinline__ void mfma_core_1024(
    const bf16* __restrict__ A, const bf16* __restrict__ B,
    int m0, int n0, bf16* sA, f32x4 acc[4][4])
{
    const int tid = threadIdx.x, lane = tid & 63, wave = tid >> 6;
    const int l15 = lane & 15, lg = lane >> 4;
    const int wr = wave >> 1, wc = wave & 1;
    bf16* sB = sA + 16 * 512;

    const bf16* gsrc = (wave < 2) ? A : B;
    const int   gm0  = (wave < 2) ? m0 : n0;
    bf16*       sdst = (wave < 2) ? sA : sB;
    const int   wv2  = wave & 1;

#define STAGE(k0_) { \
    _Pragma("unroll") for (int u = 0; u < 8; ++u) { \
        const int c = wv2 * 8 + u; \
        const int mg = c >> 1, s = c & 1; \
        gload_lds16(gsrc + (size_t)(gm0 + mg * 16 + l15) * DIM + (k0_) + s * 32 + lg * 8, \
                    sdst + c * 512); \
    } }

    STAGE(0);
#pragma unroll 1
    for (int t = 0; t < DIM / 64; ++t) {
        __syncthreads();
#pragma unroll
        for (int s = 0; s < 2; ++s) {
            bf16x8 af[4], bfr[4];
#pragma unroll
            for (int i = 0; i < 4; ++i)
                af[i] = *(const bf16x8*)(sA + ((wr * 4 + i) * 2 + s) * 512 + lane * 8);
#pragma unroll
            for (int j = 0; j < 4; ++j)
                bfr[j] = *(const bf16x8*)(sB + ((wc * 4 + j) * 2 + s) * 512 + lane * 8);
#pragma unroll
            for (int i = 0; i < 4; ++i)
#pragma unroll
                for (int j = 0; j < 4; ++j)
                    acc[i][j] = MFMA16(af[i], bfr[j], acc[i][j]);
        }
        __syncthreads();
        if (t < DIM / 64 - 1) STAGE((t + 1) * 64);
    }
#undef STAGE
}

// ---------------------------------------------------------------------------
// Kernel 1: QKV projections via MFMA.  Q/K out (B,H,S,D); V out (B,H,D,S).
// ---------------------------------------------------------------------------
__global__ __launch_bounds__(256) void proj_mfma_kernel(
    const bf16* __restrict__ Xq, const bf16* __restrict__ Xk, const bf16* __restrict__ Xv,
    const bf16* __restrict__ Wq, const bf16* __restrict__ Wk, const bf16* __restrict__ Wv,
    bf16* __restrict__ qo, bf16* __restrict__ ko, bf16* __restrict__ vo)
{
    __shared__ alignas(16) bf16 smem[16384];   // 32 KB
    const int z = blockIdx.z;
    const bf16* X = z == 0 ? Xq : z == 1 ? Xk : Xv;
    const bf16* W = z == 0 ? Wq : z == 1 ? Wk : Wv;
    const int m0 = blockIdx.y * 128, n0 = blockIdx.x * 128;
    f32x4 acc[4][4] = {};
    mfma_core_1024(X, W, m0, n0, smem, acc);

    const int tid = threadIdx.x, lane = tid & 63, wave = tid >> 6;
    const int l15 = lane & 15, lg = lane >> 4, wr = wave >> 1, wc = wave & 1;
    const int h = blockIdx.x * 2 + wc;     // 128-wide n-tile spans 2 heads

    if (z != 2) {
        bf16* O = z == 0 ? qo : ko;
#pragma unroll
        for (int i = 0; i < 4; ++i)
#pragma unroll
            for (int r = 0; r < 4; ++r) {
                int m = m0 + wr * 64 + i * 16 + lg * 4 + r;
                int bb = m >> 11, ss = m & (SEQ - 1);
                size_t base = ((size_t)(bb * HEADS + h) * SEQ + ss) * HDIM;
#pragma unroll
                for (int j = 0; j < 4; ++j)
                    O[base + j * 16 + l15] = __float2bfloat16(acc[i][j][r]);
            }
    } else {
#pragma unroll
        for (int i = 0; i < 4; ++i) {
            int s0 = m0 + wr * 64 + i * 16 + lg * 4;
            int bb = s0 >> 11, ss = s0 & (SEQ - 1);
#pragma unroll
            for (int j = 0; j < 4; ++j) {
                int d = j * 16 + l15;
                union { bf16 h4[4]; uint2 u; } pk;
#pragma unroll
                for (int r = 0; r < 4; ++r) pk.h4[r] = __float2bfloat16(acc[i][j][r]);
                *(uint2*)&vo[((size_t)(bb * HEADS + h) * HDIM + d) * SEQ + ss] = pk.u;
            }
        }
    }
}

// ---------------------------------------------------------------------------
// Kernel 2: causal attention, MFMA bf16, SWAPPED QK^T (S^T layout).
// mfma(K,Q): lane holds q = lane&15 (fixed), k = ct*16 + lg*4 + r.
//  - row stats: in-lane tree + shfl_xor(16,32); single (m,l) scalar per lane
//  - weights: one float4 NT store per ct (4 consecutive k)
//  - P->bf16: one packed ds_write_b64 per ct into wave-private Ps
// Softmax in exp2 domain (CS = SCALE*log2e).
// ---------------------------------------------------------------------------
__global__ __launch_bounds__(256) void attn_kernel(
    const bf16* __restrict__ qws, const bf16* __restrict__ kws, const bf16* __restrict__ vtws,
    float* __restrict__ weights, bf16* __restrict__ attn_out)
{
    __shared__ alignas(16) bf16 Ks[4096];
    __shared__ alignas(16) bf16 Vs[4096];
    __shared__ alignas(16) bf16 Ps[4096];

    const int tid  = threadIdx.x;
    const int lane = tid & 63;
    const int wave = tid >> 6;
    const int l15  = lane & 15;
    const int lg   = lane >> 4;
    const int qt = (int)gridDim.x - 1 - (int)blockIdx.x;  // heavy blocks first
    const int h  = blockIdx.y, b = blockIdx.z;
    const int bh = b * HEADS + h;
    const int q0 = qt * 64;
    const int qloc = 16 * wave + l15;      // this lane's q row within tile

    const bf16* qbase = qws + (size_t)bh * SEQ * HDIM;
    const bf16* kbase = kws + (size_t)bh * SEQ * HDIM;
    const bf16* vbase = vtws + (size_t)bh * HDIM * SEQ;

    bf16x8 qa0, qa1;
    {
        const bf16* qp = qbase + (size_t)(q0 + qloc) * HDIM + lg * 8;
        qa0 = *(const bf16x8*)qp;
        qa1 = *(const bf16x8*)(qp + 32);
    }

#define LOADK(kt_, r0, r1) { \
    const bf16* rp = kbase + (size_t)((kt_) * 64 + 16 * wave + l15) * HDIM + lg * 8; \
    r0 = *(const uint4*)rp; r1 = *(const uint4*)(rp + 32); }
#define STOREK(r0, r1) { \
    *(uint4*)&Ks[((wave * 2 + 0) * 64 + lane) * 8] = r0; \
    *(uint4*)&Ks[((wave * 2 + 1) * 64 + lane) * 8] = r1; }
#define LOADV(kt_, r0, r1) { \
    const bf16* rp = vbase + (size_t)(16 * wave + l15) * SEQ + (kt_) * 64 + lg * 8; \
    r0 = *(const uint4*)rp; r1 = *(const uint4*)(rp + 32); }
#define STOREV(r0, r1) { \
    *(uint4*)&Vs[((wave * 2 + 0) * 64 + lane) * 8] = r0; \
    *(uint4*)&Vs[((wave * 2 + 1) * 64 + lane) * 8] = r1; }
// swapped: A = K chunk, B = Q  ->  acc[ct][r] = S[q=l15][k=ct*16+lg*4+r]
#define QKT(acc_) { \
    _Pragma("unroll") \
    for (int ct = 0; ct < 4; ++ct) { \
        bf16x8 b0 = *(const bf16x8*)&Ks[((ct * 2 + 0) * 64 + lane) * 8]; \
        bf16x8 b1 = *(const bf16x8*)&Ks[((ct * 2 + 1) * 64 + lane) * 8]; \
        acc_[ct] = MFMA16(b0, qa0, acc_[ct]); \
        acc_[ct] = MFMA16(b1, qa1, acc_[ct]); \
    } }

    // ---- pass 1: online row max / sum-exp2 (scalar per-lane stats) ----
    float m_run = -1e30f;
    float l_run = 0.f;

    {
        uint4 k0, k1;
        LOADK(0, k0, k1);
        STOREK(k0, k1);
    }
    for (int kt = 0; kt <= qt; ++kt) {
        __syncthreads();
        f32x4 acc[4] = {};
        QKT(acc);
        const bool more = kt < qt;
        uint4 nk0, nk1;
        if (more) LOADK(kt + 1, nk0, nk1);
        const bool diag = (kt == qt);
        float t[4][4];
#pragma unroll
        for (int ct = 0; ct < 4; ++ct)
#pragma unroll
            for (int r = 0; r < 4; ++r) {
                float v = acc[ct][r] * CS;
                if (diag && (ct * 16 + lg * 4 + r > qloc)) v = -1e30f;
                t[ct][r] = v;
            }
        float tm = -1e30f;
#pragma unroll
        for (int ct = 0; ct < 4; ++ct)
#pragma unroll
            for (int r = 0; r < 4; ++r) tm = fmaxf(tm, t[ct][r]);
        tm = fmaxf(tm, __shfl_xor(tm, 16));
        tm = fmaxf(tm, __shfl_xor(tm, 32));
        float mn = fmaxf(m_run, tm);
        float ps = 0.f;
#pragma unroll
        for (int ct = 0; ct < 4; ++ct)
#pragma unroll
            for (int r = 0; r < 4; ++r) ps += EXP2F(t[ct][r] - mn);
        ps += __shfl_xor(ps, 16);
        ps += __shfl_xor(ps, 32);
        l_run = l_run * EXP2F(m_run - mn) + ps;
        m_run = mn;
        __syncthreads();
        if (more) STOREK(nk0, nk1);
    }

    const float il = 1.0f / l_run;

    // ---- pass 2: weights + PV ----
    {
        uint4 k0, k1, v0, v1;
        LOADK(0, k0, k1);
        LOADV(0, v0, v1);
        STOREK(k0, k1);
        STOREV(v0, v1);
    }
    f32x4 oacc[4] = {};
    const size_t wrow = ((size_t)bh * SEQ + q0 + qloc) * SEQ;

    for (int kt = 0; kt <= qt; ++kt) {
        __syncthreads();
        f32x4 acc[4] = {};
        QKT(acc);
        const bool more = kt < qt;
        uint4 nk0, nk1, nv0, nv1;
        if (more) { LOADK(kt + 1, nk0, nk1); LOADV(kt + 1, nv0, nv1); }
        const bool diag = (kt == qt);
#pragma unroll
        for (int ct = 0; ct < 4; ++ct) {
            f32x4 w4;
            union { bf16 h4[4]; uint2 u; } pk;
#pragma unroll
            for (int r = 0; r < 4; ++r) {
                float v = acc[ct][r] * CS;
                if (diag && (ct * 16 + lg * 4 + r > qloc)) v = -1e30f;
                float w = EXP2F(v - m_run) * il;
                w4[r] = w;
                pk.h4[r] = __float2bfloat16(w);
            }
            __builtin_nontemporal_store(
                w4, (f32x4*)&weights[wrow + kt * 64 + ct * 16 + lg * 4]);
            // packed P transpose into wave-private LDS (A-fragment layout):
            // elem = ((wave*2 + (ct>>1))*64 + ((ct&1)*2 + (lg>>1))*16 + l15)*8
            //        + (lg&1)*4
            *(uint2*)&Ps[(((wave * 2 + (ct >> 1)) * 64
                           + ((ct & 1) * 2 + (lg >> 1)) * 16 + l15) * 8
                          + (lg & 1) * 4)] = pk.u;
        }
        // PV: Ps is wave-private; compiler orders ds_write -> ds_read.
        bf16x8 pa0 = *(const bf16x8*)&Ps[((wave * 2 + 0) * 64 + lane) * 8];
        bf16x8 pa1 = *(const bf16x8*)&Ps[((wave * 2 + 1) * 64 + lane) * 8];
#pragma unroll
        for (int td = 0; td < 4; ++td) {
            bf16x8 vb0 = *(const bf16x8*)&Vs[((td * 2 + 0) * 64 + lane) * 8];
            bf16x8 vb1 = *(const bf16x8*)&Vs[((td * 2 + 1) * 64 + lane) * 8];
            oacc[td] = MFMA16(pa0, vb0, oacc[td]);
            oacc[td] = MFMA16(pa1, vb1, oacc[td]);
        }
        __syncthreads();
        if (more) { STOREK(nk0, nk1); STOREV(nv0, nv1); }
    }

    // O tile write: (b, s, h*64 + d) bf16  (row q = lg*4+r, col d = td*16+l15)
#pragma unroll
    for (int td = 0; td < 4; ++td)
#pragma unroll
        for (int r = 0; r < 4; ++r) {
            int rowg = q0 + 16 * wave + lg * 4 + r;
            attn_out[((size_t)b * SEQ + rowg) * DIM + h * HDIM + td * 16 + l15]
                = __float2bfloat16(oacc[td][r]);
        }

    // zero-fill masked (upper-triangle) weight columns (streaming NT stores)
    const int zc0 = (qt + 1) * 64;
    if (zc0 < SEQ) {
        const int nc4 = (SEQ - zc0) >> 2;
        const size_t base = ((size_t)bh * SEQ + q0) * SEQ + zc0;
        const f32x4 z = {0.f, 0.f, 0.f, 0.f};
        for (int r = 0; r < 64; ++r)
            for (int c = tid; c < nc4; c += 256)
                __builtin_nontemporal_store(
                    z, (f32x4*)&weights[base + (size_t)r * SEQ + (size_t)c * 4]);
    }
#undef LOADK
#undef STOREK
#undef LOADV
#undef STOREV
#undef QKT
}

// ---------------------------------------------------------------------------
// Kernel 3: output projection via MFMA, fp32 out + bias.
// ---------------------------------------------------------------------------
__global__ __launch_bounds__(256) void oproj_mfma_kernel(
    const bf16* __restrict__ A, const bf16* __restrict__ Wo,
    const float* __restrict__ bo, float* __restrict__ out)
{
    __shared__ alignas(16) bf16 smem[16384];
    const int m0 = blockIdx.y * 128, n0 = blockIdx.x * 128;
    f32x4 acc[4][4] = {};
    mfma_core_1024(A, Wo, m0, n0, smem, acc);

    const int tid = threadIdx.x, lane = tid & 63, wave = tid >> 6;
    const int l15 = lane & 15, lg = lane >> 4, wr = wave >> 1, wc = wave & 1;
    float bv[4];
#pragma unroll
    for (int j = 0; j < 4; ++j) bv[j] = bo[n0 + wc * 64 + j * 16 + l15];
#pragma unroll
    for (int i = 0; i < 4; ++i)
#pragma unroll
        for (int r = 0; r < 4; ++r) {
            int m = m0 + wr * 64 + i * 16 + lg * 4 + r;
#pragma unroll
            for (int j = 0; j < 4; ++j)
                out[(size_t)m * DIM + n0 + wc * 64 + j * 16 + l15] = acc[i][j][r] + bv[j];
        }
}

// ---------------------------------------------------------------------------
extern "C" void kernel_launch(void* const* d_in, const int* in_sizes, int n_in,
                              void* d_out, int out_size, void* d_ws, size_t ws_size,
                              hipStream_t stream)
{
    const float* Q  = (const float*)d_in[0];
    const float* K  = (const float*)d_in[1];
    const float* V  = (const float*)d_in[2];
    const float* Wq = (const float*)d_in[3];
    const float* Wk = (const float*)d_in[4];
    const float* Wv = (const float*)d_in[5];
    const float* Wo = (const float*)d_in[6];
    const float* bo = (const float*)d_in[7];

    float* out     = (float*)d_out;
    float* weights = out + (size_t)BS * DIM;   // 268,435,456 floats

    // Pre-attn bf16 scratch lives in the TAIL of the weights buffer; its only
    // readers (proj_mfma) complete before attn overwrites all of weights.
    const size_t XN = (size_t)BS * DIM;        // 8,388,608
    const size_t WN = (size_t)DIM * DIM;       // 1,048,576
    const size_t scratch_elems = 3 * XN + 3 * WN;   // bf16 elements
    bf16* cvt = (bf16*)(weights + ((size_t)268435456 - scratch_elems / 2));
    bf16* xq  = cvt;
    bf16* xk  = xq + XN;
    bf16* xv  = xk + XN;
    bf16* wqc = xv + XN;
    bf16* wkc = wqc + WN;
    bf16* wvc = wkc + WN;

    bf16* qws  = (bf16*)d_ws;                  // (B,H,S,D)  bf16
    bf16* kws  = qws + (size_t)BS * DIM;       // (B,H,S,D)  bf16
    bf16* vtws = kws + (size_t)BS * DIM;       // (B,H,D,S)  bf16 (transposed)
    bf16* aws  = vtws + (size_t)BS * DIM;      // (B,S,DIM)  bf16
    bf16* woc  = qws;                          // reuse qws region AFTER attn

    dim3 blk(256);
    cvt_kernel<<<dim3(4096, 6), blk, 0, stream>>>(
        Q, K, V, Wq, Wk, Wv, xq, xk, xv, wqc, wkc, wvc);
    proj_mfma_kernel<<<dim3(DIM / 128, BS / 128, 3), blk, 0, stream>>>(
        xq, xk, xv, wqc, wkc, wvc, qws, kws, vtws);
    attn_kernel<<<dim3(SEQ / 64, HEADS, BATCH), blk, 0, stream>>>(
        qws, kws, vtws, weights, aws);
    cvt_wo_kernel<<<dim3(WN / (256 * 8)), blk, 0, stream>>>(Wo, woc);
    oproj_mfma_kernel<<<dim3(DIM / 128, BS / 128), blk, 0, stream>>>(
        aws, woc, bo, out);
}